// Round 1
// baseline (44.775 us; speedup 1.0000x reference)
//
#include <hip/hip_runtime.h>

// MultiOrdinalCutoffs: B=524288 rows, T=16 tasks, Cmax=63 padded cutoffs.
// diff[b,c] = mask ? input[b] - weights[ids[b],c] : 0
// pos [b,c] = mask ? weights[ids[b],c]            : 0
// mask = c < lengths[ids[b]]
// Outputs concatenated flat: diff [B*63] then pos [B*63], float32.
// Memory-bound: ~264 MB writes, ~4 MB reads.

#define CMAX 63
#define NTASK 16

__global__ __launch_bounds__(256) void moc_kernel(
    const float* __restrict__ inp,      // [B]
    const int* __restrict__ ids,        // [B]
    const float* __restrict__ weights,  // [NTASK * CMAX]
    const int* __restrict__ lengths,    // [NTASK]
    float* __restrict__ out_diff,       // [B*CMAX]
    float* __restrict__ out_pos,        // [B*CMAX]
    int total)                          // B*CMAX (divisible by 4)
{
    __shared__ float w_lds[NTASK * CMAX];
    __shared__ int   len_lds[NTASK];
    for (int i = threadIdx.x; i < NTASK * CMAX; i += blockDim.x)
        w_lds[i] = weights[i];
    if (threadIdx.x < NTASK)
        len_lds[threadIdx.x] = lengths[threadIdx.x];
    __syncthreads();

    const int nvec = total >> 2;  // float4 elements
    const int stride = gridDim.x * blockDim.x;
    for (int v = blockIdx.x * blockDim.x + threadIdx.x; v < nvec; v += stride) {
        const int base = v << 2;  // flat element index of component 0
        float4 dv, pv;
        float* dvp = &dv.x;
        float* pvp = &pv.x;
#pragma unroll
        for (int j = 0; j < 4; ++j) {
            const int idx = base + j;
            const int b = idx / CMAX;          // magic-multiply, constant 63
            const int c = idx - b * CMAX;
            const int t = ids[b];              // L1-broadcast within a row
            const float x = inp[b];
            const float w = w_lds[t * CMAX + c];
            const bool valid = c < len_lds[t];
            dvp[j] = valid ? (x - w) : 0.0f;
            pvp[j] = valid ? w : 0.0f;
        }
        reinterpret_cast<float4*>(out_diff)[v] = dv;
        reinterpret_cast<float4*>(out_pos)[v]  = pv;
    }
}

extern "C" void kernel_launch(void* const* d_in, const int* in_sizes, int n_in,
                              void* d_out, int out_size, void* d_ws, size_t ws_size,
                              hipStream_t stream) {
    const float* inp     = (const float*)d_in[0];   // [B,1]
    const int*   ids     = (const int*)d_in[1];     // [B]
    const float* weights = (const float*)d_in[2];   // [T, Cmax]
    const int*   lengths = (const int*)d_in[3];     // [T]

    const int B = in_sizes[0];            // 524288
    const int total = B * CMAX;           // per-output element count
    float* out_diff = (float*)d_out;
    float* out_pos  = (float*)d_out + total;

    const int block = 256;
    const int grid = 2048;  // grid-stride; ~16 vec4 iters/thread
    moc_kernel<<<grid, block, 0, stream>>>(inp, ids, weights, lengths,
                                           out_diff, out_pos, total);
}

// Round 2
// 42.822 us; speedup vs baseline: 1.0456x; 1.0456x over previous
//
#include <hip/hip_runtime.h>

// MultiOrdinalCutoffs: B=524288 rows, T=16 tasks, Cmax=63 padded cutoffs.
// diff[b,c] = mask ? input[b] - weights[ids[b],c] : 0
// pos [b,c] = mask ? weights[ids[b],c]            : 0
// mask = c < lengths[ids[b]]
// Outputs concatenated flat: diff [B*63] then pos [B*63], float32.
//
// Write-bound: 264 MB stores vs ~4 MB reads. Structure: each block owns
// exactly 256 rows = 16128 elements = 4032 float4 per output (exact since
// B = 2048*256). Per-row (x, t, len) staged in LDS with one coalesced
// load each; hot loop is LDS-read + float4-store only (no global loads).

#define CMAX 63
#define NTASK 16
#define ROWS_PER_BLOCK 256
#define ELEMS_PER_BLOCK (ROWS_PER_BLOCK * CMAX)   // 16128
#define VECS_PER_BLOCK (ELEMS_PER_BLOCK / 4)      // 4032

__global__ __launch_bounds__(256) void moc_kernel(
    const float* __restrict__ inp,      // [B]
    const int* __restrict__ ids,        // [B]
    const float* __restrict__ weights,  // [NTASK * CMAX]
    const int* __restrict__ lengths,    // [NTASK]
    float* __restrict__ out_diff,       // [B*CMAX]
    float* __restrict__ out_pos,        // [B*CMAX]
    int B)
{
    __shared__ float w_lds[NTASK * CMAX];        // 4032 B
    __shared__ float x_lds[ROWS_PER_BLOCK];      // per-row input
    __shared__ int   t_lds[ROWS_PER_BLOCK];      // per-row task id
    __shared__ int   len_lds[ROWS_PER_BLOCK];    // per-row valid length

    const int tid = threadIdx.x;

    // Stage cutoff table (4 KB, broadcast-read later).
    for (int i = tid; i < NTASK * CMAX; i += ROWS_PER_BLOCK)
        w_lds[i] = weights[i];

    // Stage this block's 256 rows: one coalesced dword load per array.
    const int row = blockIdx.x * ROWS_PER_BLOCK + tid;
    if (row < B) {
        const int t = ids[row];
        x_lds[tid]   = inp[row];
        t_lds[tid]   = t;
        len_lds[tid] = lengths[t];   // 16-entry table, L1-resident
    }
    __syncthreads();

    // Hot loop: 16 iterations of pure LDS-read + 2x global_store_dwordx4.
    const int ebase = blockIdx.x * ELEMS_PER_BLOCK;
    float4* __restrict__ od = reinterpret_cast<float4*>(out_diff + ebase);
    float4* __restrict__ op = reinterpret_cast<float4*>(out_pos + ebase);

    for (int v = tid; v < VECS_PER_BLOCK; v += ROWS_PER_BLOCK) {
        const int lbase = v << 2;   // local element index of component 0
        float4 dv, pv;
        float* dvp = &dv.x;
        float* pvp = &pv.x;
#pragma unroll
        for (int j = 0; j < 4; ++j) {
            const int li = lbase + j;
            const int bl = li / CMAX;           // magic-mul, constant 63
            const int c  = li - bl * CMAX;
            const float x   = x_lds[bl];        // ~broadcast across lanes
            const int   t   = t_lds[bl];
            const int   len = len_lds[bl];
            const float w   = w_lds[t * CMAX + c];
            const bool valid = c < len;
            dvp[j] = valid ? (x - w) : 0.0f;
            pvp[j] = valid ? w : 0.0f;
        }
        od[v] = dv;
        op[v] = pv;
    }
}

extern "C" void kernel_launch(void* const* d_in, const int* in_sizes, int n_in,
                              void* d_out, int out_size, void* d_ws, size_t ws_size,
                              hipStream_t stream) {
    const float* inp     = (const float*)d_in[0];   // [B,1]
    const int*   ids     = (const int*)d_in[1];     // [B]
    const float* weights = (const float*)d_in[2];   // [T, Cmax]
    const int*   lengths = (const int*)d_in[3];     // [T]

    const int B = in_sizes[0];            // 524288 = 2048 * 256
    const int total = B * CMAX;
    float* out_diff = (float*)d_out;
    float* out_pos  = (float*)d_out + total;

    const int grid = (B + ROWS_PER_BLOCK - 1) / ROWS_PER_BLOCK;  // 2048
    moc_kernel<<<grid, ROWS_PER_BLOCK, 0, stream>>>(inp, ids, weights, lengths,
                                                    out_diff, out_pos, B);
}